// Round 11
// baseline (884.721 us; speedup 1.0000x reference)
//
#include <hip/hip_runtime.h>

#define BB 256
#define TT 1024
#define II 128
#define HH 64
#define BT (BB * TT)

typedef _Float16 h2 __attribute__((ext_vector_type(2)));
typedef _Float16 half8 __attribute__((ext_vector_type(8)));
typedef float f32x4 __attribute__((ext_vector_type(4)));
typedef unsigned int uint;
typedef unsigned short ushort;

#define DOT2(a, b, c) __builtin_amdgcn_fdot2((a), (b), (c), false)
#define BC(u) __builtin_bit_cast(h2, (uint)(u))
#define MFMA16(a, b, c) __builtin_amdgcn_mfma_f32_16x16x32_f16((a), (b), (c), 0, 0, 0)
#define RCP(v) __builtin_amdgcn_rcpf(v)

// lgkm-only barrier (R9): cross-wave data flows through LDS only.
#define BAR() asm volatile("s_waitcnt lgkmcnt(0)\n\ts_barrier" ::: "memory")

#define LDPK(P, ptr) uint P; { float2 _f = *(const float2*)(ptr); \
    h2 _h; _h[0] = (_Float16)_f.x; _h[1] = (_Float16)_f.y; \
    P = __builtin_bit_cast(uint, _h); }
#define PIN8(a,b,c,d,e,f,g,h_) asm volatile("" : "+v"(a),"+v"(b),"+v"(c),"+v"(d),"+v"(e),"+v"(f),"+v"(g),"+v"(h_));
#define LD8(P, base, o) \
    LDPK(P##0,(base)+(o)+ 0) LDPK(P##1,(base)+(o)+ 2) LDPK(P##2,(base)+(o)+ 4) LDPK(P##3,(base)+(o)+ 6) \
    LDPK(P##4,(base)+(o)+ 8) LDPK(P##5,(base)+(o)+10) LDPK(P##6,(base)+(o)+12) LDPK(P##7,(base)+(o)+14) \
    PIN8(P##0,P##1,P##2,P##3,P##4,P##5,P##6,P##7)

// 8 packs vs 2 broadcast uint4 (16 vals) into explicit acc chain c0..c3
#define D8A(P, va, vb, c0, c1, c2, c3) \
    c0 = DOT2(BC(P##0), BC((va).x), c0); c1 = DOT2(BC(P##1), BC((va).y), c1); \
    c2 = DOT2(BC(P##2), BC((va).z), c2); c3 = DOT2(BC(P##3), BC((va).w), c3); \
    c0 = DOT2(BC(P##4), BC((vb).x), c0); c1 = DOT2(BC(P##5), BC((vb).y), c1); \
    c2 = DOT2(BC(P##6), BC((vb).z), c2); c3 = DOT2(BC(P##7), BC((vb).w), c3);

// two 64-wide row dots (rows A and B) over hv0..hv7 -> sA, sB
#define DUALDOT(sA, sB) { \
    float a0=0.f,a1=0.f,a2=0.f,a3=0.f, b0=0.f,b1=0.f,b2=0.f,b3=0.f; \
    D8A(A0, hv0, hv1, a0,a1,a2,a3) D8A(A1, hv2, hv3, a0,a1,a2,a3) \
    D8A(A2, hv4, hv5, a0,a1,a2,a3) D8A(A3, hv6, hv7, a0,a1,a2,a3) \
    D8A(B0, hv0, hv1, b0,b1,b2,b3) D8A(B1, hv2, hv3, b0,b1,b2,b3) \
    D8A(B2, hv4, hv5, b0,b1,b2,b3) D8A(B3, hv6, hv7, b0,b1,b2,b3) \
    sA = (a0 + a1) + (a2 + a3); sB = (b0 + b1) + (b2 + b3); }

// ============ Kernel A: xg[bt][r] = x[bt,:] . w_ih0[r,:]  (f16) — R7/R9 ======
__global__ __launch_bounds__(256)
void xg_mfma(const float* __restrict__ x, const float* __restrict__ w_ih0,
             ushort* __restrict__ xg)
{
    __shared__ __align__(16) _Float16 xt[64][136];
    __shared__ __align__(16) _Float16 wt[128][136];
    const int tid = threadIdx.x, lane = tid & 63, wv = tid >> 6;
    const int bt0 = blockIdx.x * 64;
    {
        const int row = tid >> 2, q = (tid & 3) * 32;
        const float4* src = (const float4*)(x + (size_t)(bt0 + row) * II + q);
        _Float16* dst = &xt[row][q];
        #pragma unroll
        for (int i = 0; i < 8; ++i) {
            float4 v = src[i];
            dst[4*i+0]=(_Float16)v.x; dst[4*i+1]=(_Float16)v.y;
            dst[4*i+2]=(_Float16)v.z; dst[4*i+3]=(_Float16)v.w;
        }
    }
    for (int nh = 0; nh < 2; ++nh) {
        __syncthreads();
        {
            const int n = tid >> 1, kh = (tid & 1) * 64;
            const float4* src = (const float4*)(w_ih0 + (size_t)(nh * 128 + n) * II + kh);
            _Float16* dst = &wt[n][kh];
            #pragma unroll
            for (int i = 0; i < 16; ++i) {
                float4 v = src[i];
                dst[4*i+0]=(_Float16)v.x; dst[4*i+1]=(_Float16)v.y;
                dst[4*i+2]=(_Float16)v.z; dst[4*i+3]=(_Float16)v.w;
            }
        }
        __syncthreads();
        const int m = wv * 16 + (lane & 15);
        const int kf = (lane >> 4) * 8;
        half8 a0 = *(const half8*)&xt[m][ 0 + kf];
        half8 a1 = *(const half8*)&xt[m][32 + kf];
        half8 a2 = *(const half8*)&xt[m][64 + kf];
        half8 a3 = *(const half8*)&xt[m][96 + kf];
        #pragma unroll
        for (int nt = 0; nt < 8; ++nt) {
            const int nloc = nt * 16 + (lane & 15);
            half8 b0 = *(const half8*)&wt[nloc][ 0 + kf];
            half8 b1 = *(const half8*)&wt[nloc][32 + kf];
            half8 b2 = *(const half8*)&wt[nloc][64 + kf];
            half8 b3 = *(const half8*)&wt[nloc][96 + kf];
            f32x4 acc = {0.f, 0.f, 0.f, 0.f};
            acc = MFMA16(a0, b0, acc); acc = MFMA16(a1, b1, acc);
            acc = MFMA16(a2, b2, acc); acc = MFMA16(a3, b3, acc);
            const int col = nh * 128 + nt * 16 + (lane & 15);
            const int r0  = wv * 16 + (lane >> 4) * 4;
            #pragma unroll
            for (int r = 0; r < 4; ++r) {
                _Float16 hv = (_Float16)acc[r];
                xg[(size_t)(bt0 + r0 + r) * 256 + col] = __builtin_bit_cast(ushort, hv);
            }
        }
    }
}

// ============ Kernel B: 6-wave pipelined recurrence ==========================
// Roles (2 waves each, lane = (gp, j): gp = gate pair {i,f}/{g,o}, j = hidden):
//  P  (w0,w1): h0(k)   = lstm0(xg(k), h0(k-1))           [W_hh0, 64 packs]
//  Q1 (w2,w3): z(k-1)  = W_ih1 . h0(k-1) + bias1         [W_ih1, 64 packs]
//  Q2 (w4,w5): h1(k-2) = act(z(k-2) + W_hh1 . h1(k-3))   [W_hh1, 64 packs]
// 64 packs + ~60 working ~= 125 VGPRs — UNDER the allocator's ~132 cap, so
// weights finally live in arch VGPRs (R10: 128 packs forced AGPR parking,
// ~2x issue). Gate gather = ONE shfl_xor(32) of the two activated values;
// activations split across the pair (2 transcendentals/lane); c/h redundant
// x2. Recurrences stay whole within one wave (R10 lesson: splitting a
// recurrence across waves adds a barrier to its serial loop).
__global__ __launch_bounds__(384) __attribute__((amdgpu_waves_per_eu(1, 1)))
void lstm2_core(const float* __restrict__ w_hh0,
                const float* __restrict__ b_ih0, const float* __restrict__ b_hh0,
                const float* __restrict__ w_ih1, const float* __restrict__ w_hh1,
                const float* __restrict__ b_ih1, const float* __restrict__ b_hh1,
                const ushort* __restrict__ xg, ushort* __restrict__ h1g)
{
    const int bb   = blockIdx.x;
    const int w    = threadIdx.x >> 6;
    const int l    = threadIdx.x & 63;
    const int role = w >> 1;                  // 0=P, 1=Q1, 2=Q2
    const int gp   = l >> 5;                  // 0: gates {i,f}, 1: gates {g,o}
    const int j    = (w & 1) * 32 + (l & 31); // hidden index
    const int rA   = gp * 128 + j;            // gate row (i or g)
    const int rB   = rA + 64;                 // gate row (f or o)

    __shared__ __align__(16) uint h0buf[2][32];   // 64 f16
    __shared__ __align__(16) uint h1buf[2][32];
    __shared__ float zbuf[2][4][68];              // layer-1 z (f32, padded)

    const float* M = (role == 0) ? w_hh0 : (role == 1) ? w_ih1 : w_hh1;
    const float* pA = M + (size_t)rA * 64;
    const float* pB = M + (size_t)rB * 64;
    LD8(A0, pA,  0) LD8(A1, pA, 16) LD8(A2, pA, 32) LD8(A3, pA, 48)
    LD8(B0, pB,  0) LD8(B1, pB, 16) LD8(B2, pB, 32) LD8(B3, pB, 48)

    float bA = 0.f, bB = 0.f;
    if (role == 0)      { bA = b_ih0[rA] + b_hh0[rA]; bB = b_ih0[rB] + b_hh0[rB]; }
    else if (role == 1) { bA = b_ih1[rA] + b_hh1[rA]; bB = b_ih1[rB] + b_hh1[rB]; }

    // actA: gp=0 -> sigmoid (gate i), gp=1 -> tanh (gate g); actB always sigmoid
    const float nscA = gp ?  2.0f : -1.0f;
    const float acoA = gp ?  1.0f :  0.0f;
    const float bcoA = gp ? -1.0f :  1.0f;

    float cst = 0.0f;
    const ushort* xbA = xg + (size_t)bb * TT * 256 + rA;   // role 0 only
    const ushort* xbB = xg + (size_t)bb * TT * 256 + rB;
    ushort* h1b = h1g + (size_t)bb * TT * 64 + j;          // role 2, gp==0

    if (threadIdx.x < 32)      h0buf[1][threadIdx.x] = 0u;
    else if (threadIdx.x < 64) h1buf[1][threadIdx.x - 32] = 0u;
    __syncthreads();

    ushort xcA = 0, xcB = 0, x1A = 0, x1B = 0, x2A = 0, x2B = 0;
    if (role == 0) {
        xcA = xbA[0];   xcB = xbB[0];
        x1A = xbA[256]; x1B = xbB[256];
    }

    for (int k = 0; k < TT + 2; ++k) {
        if (role == 0) {
            if (k + 2 < TT) { x2A = xbA[(size_t)(k + 2) * 256];
                              x2B = xbB[(size_t)(k + 2) * 256]; }
            if (k < TT) {
                const uint4* hq = (const uint4*)&h0buf[(k + 1) & 1][0];
                uint4 hv0=hq[0], hv1=hq[1], hv2=hq[2], hv3=hq[3];
                uint4 hv4=hq[4], hv5=hq[5], hv6=hq[6], hv7=hq[7];
                float sA, sB;
                DUALDOT(sA, sB)
                sA += bA + (float)__builtin_bit_cast(_Float16, xcA);
                sB += bB + (float)__builtin_bit_cast(_Float16, xcB);
                float yA   = __expf(nscA * sA);
                float actA = fmaf(acoA, yA, bcoA) * RCP(yA + 1.0f);
                float actB = RCP(1.0f + __expf(-sB));
                float oA = __shfl_xor(actA, 32, 64);
                float oB = __shfl_xor(actB, 32, 64);
                float ii = gp ? oA : actA;
                float ff = gp ? oB : actB;
                float gg = gp ? actA : oA;
                float oo = gp ? actB : oB;
                cst = fmaf(ff, cst, ii * gg);
                float hval = oo * (1.0f - 2.0f * RCP(1.0f + __expf(2.0f * cst)));
                if (gp == 0) ((_Float16*)&h0buf[k & 1][0])[j] = (_Float16)hval;
            }
            xcA = x1A; xcB = x1B; x1A = x2A; x1B = x2B;
        } else if (role == 1) {
            if (k >= 1 && k <= TT) {
                const int m = k - 1, s = m & 1;
                const uint4* hq = (const uint4*)&h0buf[s][0];
                uint4 hv0=hq[0], hv1=hq[1], hv2=hq[2], hv3=hq[3];
                uint4 hv4=hq[4], hv5=hq[5], hv6=hq[6], hv7=hq[7];
                float sA, sB;
                DUALDOT(sA, sB)
                zbuf[s][2 * gp][j]     = sA + bA;
                zbuf[s][2 * gp + 1][j] = sB + bB;
            }
        } else {
            if (k >= 2) {
                const int m = k - 2, s = m & 1;
                const uint4* hq = (const uint4*)&h1buf[(m + 1) & 1][0];  // h1(m-1)
                uint4 hv0=hq[0], hv1=hq[1], hv2=hq[2], hv3=hq[3];
                uint4 hv4=hq[4], hv5=hq[5], hv6=hq[6], hv7=hq[7];
                float sA, sB;
                DUALDOT(sA, sB)
                sA += zbuf[s][2 * gp][j];
                sB += zbuf[s][2 * gp + 1][j];
                float yA   = __expf(nscA * sA);
                float actA = fmaf(acoA, yA, bcoA) * RCP(yA + 1.0f);
                float actB = RCP(1.0f + __expf(-sB));
                float oA = __shfl_xor(actA, 32, 64);
                float oB = __shfl_xor(actB, 32, 64);
                float ii = gp ? oA : actA;
                float ff = gp ? oB : actB;
                float gg = gp ? actA : oA;
                float oo = gp ? actB : oB;
                cst = fmaf(ff, cst, ii * gg);
                float hval = oo * (1.0f - 2.0f * RCP(1.0f + __expf(2.0f * cst)));
                if (gp == 0) {
                    _Float16 hf = (_Float16)hval;
                    ((_Float16*)&h1buf[s][0])[j] = hf;
                    h1b[(size_t)m * 64] = __builtin_bit_cast(ushort, hf);
                }
            }
        }
        BAR();
    }
}

// ============ Kernel C: out[bt] = sigmoid(h1g[bt,:] . w_out + b_out) =========
__global__ __launch_bounds__(256)
void head_gemv(const ushort* __restrict__ h1g, const float* __restrict__ w_out,
               const float* __restrict__ b_out, float* __restrict__ outp)
{
    __shared__ float wsh[64];
    const int tid = threadIdx.x;
    if (tid < 64) wsh[tid] = w_out[tid];
    __syncthreads();
    const int bt = blockIdx.x * 256 + tid;
    const uint4* hp = (const uint4*)(h1g + (size_t)bt * 64);
    float s = 0.0f;
    #pragma unroll
    for (int i = 0; i < 8; ++i) {
        uint4 v = hp[i];
        const float* wp = &wsh[8 * i];
        h2 p;
        p = BC(v.x); s = fmaf((float)p[0], wp[0], s); s = fmaf((float)p[1], wp[1], s);
        p = BC(v.y); s = fmaf((float)p[0], wp[2], s); s = fmaf((float)p[1], wp[3], s);
        p = BC(v.z); s = fmaf((float)p[0], wp[4], s); s = fmaf((float)p[1], wp[5], s);
        p = BC(v.w); s = fmaf((float)p[0], wp[6], s); s = fmaf((float)p[1], wp[7], s);
    }
    outp[bt] = RCP(1.0f + __expf(-(s + b_out[0])));
}

extern "C" void kernel_launch(void* const* d_in, const int* in_sizes, int n_in,
                              void* d_out, int out_size, void* d_ws, size_t ws_size,
                              hipStream_t stream) {
    const float* x     = (const float*)d_in[0];
    const float* w_ih0 = (const float*)d_in[1];
    const float* w_hh0 = (const float*)d_in[2];
    const float* b_ih0 = (const float*)d_in[3];
    const float* b_hh0 = (const float*)d_in[4];
    const float* w_ih1 = (const float*)d_in[5];
    const float* w_hh1 = (const float*)d_in[6];
    const float* b_ih1 = (const float*)d_in[7];
    const float* b_hh1 = (const float*)d_in[8];
    const float* w_out = (const float*)d_in[9];
    const float* b_out = (const float*)d_in[10];
    float* out = (float*)d_out;

    ushort* xg  = (ushort*)d_ws;                                   // 128 MiB
    ushort* h1g = (ushort*)((char*)d_ws + (size_t)BT * 256 * 2);   //  32 MiB

    hipLaunchKernelGGL(xg_mfma, dim3(BT / 64), dim3(256), 0, stream, x, w_ih0, xg);
    hipLaunchKernelGGL(lstm2_core, dim3(BB), dim3(384), 0, stream,
                       w_hh0, b_ih0, b_hh0, w_ih1, w_hh1, b_ih1, b_hh1, xg, h1g);
    hipLaunchKernelGGL(head_gemv, dim3(BT / 256), dim3(256), 0, stream,
                       h1g, w_out, b_out, out);
}

// Round 12
// 823.720 us; speedup vs baseline: 1.0741x; 1.0741x over previous
//
#include <hip/hip_runtime.h>

#define BB 256
#define TT 1024
#define II 128
#define HH 64
#define BT (BB * TT)

typedef _Float16 h2 __attribute__((ext_vector_type(2)));
typedef _Float16 half8 __attribute__((ext_vector_type(8)));
typedef float f32x4 __attribute__((ext_vector_type(4)));
typedef unsigned int uint;
typedef unsigned short ushort;

#define DOT2(a, b, c) __builtin_amdgcn_fdot2((a), (b), (c), false)
#define BC(u) __builtin_bit_cast(h2, (uint)(u))
#define MFMA16(a, b, c) __builtin_amdgcn_mfma_f32_16x16x32_f16((a), (b), (c), 0, 0, 0)
#define SIG(v) __builtin_amdgcn_rcpf(1.0f + __expf(-(v)))
#define TNH(v) (1.0f - 2.0f * __builtin_amdgcn_rcpf(1.0f + __expf(2.0f * (v))))

// lgkm-only barrier (R9): cross-wave data flows through LDS only.
#define BAR() asm volatile("s_waitcnt lgkmcnt(0)\n\ts_barrier" ::: "memory")

#define LDPK(P, ptr) uint P; { float2 _f = *(const float2*)(ptr); \
    h2 _h; _h[0] = (_Float16)_f.x; _h[1] = (_Float16)_f.y; \
    P = __builtin_bit_cast(uint, _h); }
#define PIN8(a,b,c,d,e,f,g,h_) asm volatile("" : "+v"(a),"+v"(b),"+v"(c),"+v"(d),"+v"(e),"+v"(f),"+v"(g),"+v"(h_));
#define LD8(P, base, o) \
    LDPK(P##0,(base)+(o)+ 0) LDPK(P##1,(base)+(o)+ 2) LDPK(P##2,(base)+(o)+ 4) LDPK(P##3,(base)+(o)+ 6) \
    LDPK(P##4,(base)+(o)+ 8) LDPK(P##5,(base)+(o)+10) LDPK(P##6,(base)+(o)+12) LDPK(P##7,(base)+(o)+14) \
    PIN8(P##0,P##1,P##2,P##3,P##4,P##5,P##6,P##7)

#define D8A(P, va, vb, c0, c1, c2, c3) \
    c0 = DOT2(BC(P##0), BC((va).x), c0); c1 = DOT2(BC(P##1), BC((va).y), c1); \
    c2 = DOT2(BC(P##2), BC((va).z), c2); c3 = DOT2(BC(P##3), BC((va).w), c3); \
    c0 = DOT2(BC(P##4), BC((vb).x), c0); c1 = DOT2(BC(P##5), BC((vb).y), c1); \
    c2 = DOT2(BC(P##6), BC((vb).z), c2); c3 = DOT2(BC(P##7), BC((vb).w), c3);

#define GDOT(G, s) { float a0=0.f,a1=0.f,a2=0.f,a3=0.f; \
    D8A(G##A, hv0, hv1, a0,a1,a2,a3) D8A(G##B, hv2, hv3, a0,a1,a2,a3) \
    D8A(G##C, hv4, hv5, a0,a1,a2,a3) D8A(G##D, hv6, hv7, a0,a1,a2,a3) \
    s = (a0 + a1) + (a2 + a3); }

// ============ Kernel A: xg[bt][j*4+g] = x[bt,:] . w_ih0[g*64+j,:]  (f16) =====
// 256 bt-rows per block; W staged in LDS ONCE per block (the old 64-row
// version restaged W 4096x -> 512 MB of W traffic, ~150 us for a 41 us floor).
__global__ __launch_bounds__(256)
void xg_mfma(const float* __restrict__ x, const float* __restrict__ w_ih0,
             ushort* __restrict__ xg)
{
    __shared__ __align__(16) _Float16 wt[256][136];   // 69.6 KB
    __shared__ __align__(16) _Float16 xt[64][136];    // 17.4 KB
    const int tid = threadIdx.x, lane = tid & 63, wv = tid >> 6;
    const int bt0 = blockIdx.x * 256;

    // stage all 256 W rows (f32 -> f16), 2 threads per row, 2 passes
    #pragma unroll
    for (int p = 0; p < 2; ++p) {
        const int n = p * 128 + (tid >> 1), kh = (tid & 1) * 64;
        const float4* src = (const float4*)(w_ih0 + (size_t)n * II + kh);
        _Float16* dst = &wt[n][kh];
        #pragma unroll
        for (int i = 0; i < 16; ++i) {
            float4 v = src[i];
            dst[4*i+0]=(_Float16)v.x; dst[4*i+1]=(_Float16)v.y;
            dst[4*i+2]=(_Float16)v.z; dst[4*i+3]=(_Float16)v.w;
        }
    }

    for (int grp = 0; grp < 4; ++grp) {
        __syncthreads();   // grp0: W ready; grp>0: protect xt from readers
        {
            const int row = tid >> 2, q = (tid & 3) * 32;
            const float4* src = (const float4*)(x + (size_t)(bt0 + grp * 64 + row) * II + q);
            _Float16* dst = &xt[row][q];
            #pragma unroll
            for (int i = 0; i < 8; ++i) {
                float4 v = src[i];
                dst[4*i+0]=(_Float16)v.x; dst[4*i+1]=(_Float16)v.y;
                dst[4*i+2]=(_Float16)v.z; dst[4*i+3]=(_Float16)v.w;
            }
        }
        __syncthreads();

        const int m  = wv * 16 + (lane & 15);
        const int kf = (lane >> 4) * 8;
        half8 a0 = *(const half8*)&xt[m][ 0 + kf];
        half8 a1 = *(const half8*)&xt[m][32 + kf];
        half8 a2 = *(const half8*)&xt[m][64 + kf];
        half8 a3 = *(const half8*)&xt[m][96 + kf];
        #pragma unroll
        for (int nt = 0; nt < 16; ++nt) {
            const int nloc = nt * 16 + (lane & 15);
            half8 b0 = *(const half8*)&wt[nloc][ 0 + kf];
            half8 b1 = *(const half8*)&wt[nloc][32 + kf];
            half8 b2 = *(const half8*)&wt[nloc][64 + kf];
            half8 b3 = *(const half8*)&wt[nloc][96 + kf];
            f32x4 acc = {0.f, 0.f, 0.f, 0.f};
            acc = MFMA16(a0, b0, acc); acc = MFMA16(a1, b1, acc);
            acc = MFMA16(a2, b2, acc); acc = MFMA16(a3, b3, acc);
            const int col = nt * 16 + (lane & 15);          // gate-row r
            const int idx = (col & 63) * 4 + (col >> 6);    // -> [j*4+g]
            const int r0  = grp * 64 + wv * 16 + (lane >> 4) * 4;
            #pragma unroll
            for (int r = 0; r < 4; ++r) {
                _Float16 hv = (_Float16)acc[r];
                xg[(size_t)(bt0 + r0 + r) * 256 + idx] = __builtin_bit_cast(ushort, hv);
            }
        }
    }
}

// ============ Kernel B: 3-wave pipelined recurrence (R10) + unroll-2 slots ===
// Wave 0 (P):  h0(k)   = lstm0(xg(k), h0(k-1))            [W_hh0 in-lane]
// Wave 1 (Q1): z(k-1)  = W_ih1 . h0(k-1)                  [W_ih1 in-lane]
// Wave 2 (Q2): h1(k-2) = act(z(k-2) + W_hh1.h1(k-3) + b)  [W_hh1 in-lane]
// PREFETCH FIX (R11 post-mortem): the old `xc=xn1; xn1=xn2` rotation was a
// same-iteration USE of the just-issued load -> s_waitcnt vmcnt(0) for ~500
// cyc of L3 latency EVERY step. Unroll-2 with named slots xA/xB (use first,
// reload after) pushes the wait 2 barriers back -> free.
#define STEP(K_, E_, XC_) { \
    if (w == 0) { \
        if ((K_) < TT) { \
            const uint4* hq = (const uint4*)&h0buf[1-(E_)][0]; \
            uint4 hv0=hq[0], hv1=hq[1], hv2=hq[2], hv3=hq[3]; \
            uint4 hv4=hq[4], hv5=hq[5], hv6=hq[6], hv7=hq[7]; \
            float si, sf, sg, so; \
            GDOT(G0, si) GDOT(G1, sf) GDOT(G2, sg) GDOT(G3, so) \
            h2 xlo = BC((XC_).x), xhi = BC((XC_).y); \
            si += bI + (float)xlo[0]; sf += bF + (float)xlo[1]; \
            sg += bG + (float)xhi[0]; so += bO + (float)xhi[1]; \
            float ii = SIG(si), ff = SIG(sf), gg = TNH(sg), oo = SIG(so); \
            cst = fmaf(ff, cst, ii * gg); \
            float hval = oo * TNH(cst); \
            ((_Float16*)&h0buf[(E_)][0])[j] = (_Float16)hval; \
        } \
    } else if (w == 1) { \
        if ((K_) >= 1 && (K_) <= TT) { \
            const uint4* hq = (const uint4*)&h0buf[1-(E_)][0]; \
            uint4 hv0=hq[0], hv1=hq[1], hv2=hq[2], hv3=hq[3]; \
            uint4 hv4=hq[4], hv5=hq[5], hv6=hq[6], hv7=hq[7]; \
            float si, sf, sg, so; \
            GDOT(G0, si) GDOT(G1, sf) GDOT(G2, sg) GDOT(G3, so) \
            zbuf[1-(E_)][0][j] = si; zbuf[1-(E_)][1][j] = sf; \
            zbuf[1-(E_)][2][j] = sg; zbuf[1-(E_)][3][j] = so; \
        } \
    } else { \
        if ((K_) >= 2) { \
            const uint4* hq = (const uint4*)&h1buf[1-(E_)][0]; \
            uint4 hv0=hq[0], hv1=hq[1], hv2=hq[2], hv3=hq[3]; \
            uint4 hv4=hq[4], hv5=hq[5], hv6=hq[6], hv7=hq[7]; \
            float si, sf, sg, so; \
            GDOT(G0, si) GDOT(G1, sf) GDOT(G2, sg) GDOT(G3, so) \
            si += bI + zbuf[(E_)][0][j]; sf += bF + zbuf[(E_)][1][j]; \
            sg += bG + zbuf[(E_)][2][j]; so += bO + zbuf[(E_)][3][j]; \
            float ii = SIG(si), ff = SIG(sf), gg = TNH(sg), oo = SIG(so); \
            cst = fmaf(ff, cst, ii * gg); \
            float hval = oo * TNH(cst); \
            _Float16 hf = (_Float16)hval; \
            ((_Float16*)&h1buf[(E_)][0])[j] = hf; \
            h1b[(size_t)((K_) - 2) * 64] = __builtin_bit_cast(ushort, hf); \
        } \
    } }

__global__ __launch_bounds__(192) __attribute__((amdgpu_waves_per_eu(1, 1)))
void lstm2_core(const float* __restrict__ w_hh0,
                const float* __restrict__ b_ih0, const float* __restrict__ b_hh0,
                const float* __restrict__ w_ih1, const float* __restrict__ w_hh1,
                const float* __restrict__ b_ih1, const float* __restrict__ b_hh1,
                const ushort* __restrict__ xg, ushort* __restrict__ h1g)
{
    const int bb = blockIdx.x;
    const int w  = threadIdx.x >> 6;
    const int j  = threadIdx.x & 63;

    __shared__ __align__(16) uint  h0buf[2][32];
    __shared__ __align__(16) uint  h1buf[2][32];
    __shared__ float zbuf[2][4][68];

    const float* Wsel = (w == 0) ? w_hh0 : (w == 1) ? w_ih1 : w_hh1;
    const float* r0p = Wsel + (size_t)(  0 + j) * 64;
    const float* r1p = Wsel + (size_t)( 64 + j) * 64;
    const float* r2p = Wsel + (size_t)(128 + j) * 64;
    const float* r3p = Wsel + (size_t)(192 + j) * 64;
    LD8(G0A, r0p,  0) LD8(G0B, r0p, 16) LD8(G0C, r0p, 32) LD8(G0D, r0p, 48)
    LD8(G1A, r1p,  0) LD8(G1B, r1p, 16) LD8(G1C, r1p, 32) LD8(G1D, r1p, 48)
    LD8(G2A, r2p,  0) LD8(G2B, r2p, 16) LD8(G2C, r2p, 32) LD8(G2D, r2p, 48)
    LD8(G3A, r3p,  0) LD8(G3B, r3p, 16) LD8(G3C, r3p, 32) LD8(G3D, r3p, 48)

    float bI = 0.f, bF = 0.f, bG = 0.f, bO = 0.f;
    if (w == 0) {
        bI = b_ih0[j]       + b_hh0[j];
        bF = b_ih0[64 + j]  + b_hh0[64 + j];
        bG = b_ih0[128 + j] + b_hh0[128 + j];
        bO = b_ih0[192 + j] + b_hh0[192 + j];
    } else if (w == 2) {
        bI = b_ih1[j]       + b_hh1[j];
        bF = b_ih1[64 + j]  + b_hh1[64 + j];
        bG = b_ih1[128 + j] + b_hh1[128 + j];
        bO = b_ih1[192 + j] + b_hh1[192 + j];
    }

    float cst = 0.0f;
    const ushort* xbase = xg + (size_t)bb * TT * 256 + j * 4;
    ushort* h1b = h1g + (size_t)bb * TT * 64 + j;

    if (threadIdx.x < 32)       h0buf[1][threadIdx.x] = 0u;
    else if (threadIdx.x < 64)  h1buf[1][threadIdx.x - 32] = 0u;
    __syncthreads();

    uint2 xA = {0,0}, xB = {0,0};
    if (w == 0) {
        xA = *(const uint2*)(xbase);            // k = 0
        xB = *(const uint2*)(xbase + 256);      // k = 1
    }

    for (int kk = 0; kk <= TT; kk += 2) {
        // even body: k = kk (E=0): h0 rd slot1/wr slot0, z wr1/rd0, h1 rd1/wr0
        STEP(kk, 0, xA)
        if (w == 0 && kk + 2 < TT)
            xA = *(const uint2*)(xbase + (size_t)(kk + 2) * 256);
        BAR();
        // odd body: k = kk+1 (E=1)
        STEP(kk + 1, 1, xB)
        if (w == 0 && kk + 3 < TT)
            xB = *(const uint2*)(xbase + (size_t)(kk + 3) * 256);
        BAR();
    }
}

// ============ Kernel C: out[bt] = sigmoid(h1g[bt,:] . w_out + b_out) =========
__global__ __launch_bounds__(256)
void head_gemv(const ushort* __restrict__ h1g, const float* __restrict__ w_out,
               const float* __restrict__ b_out, float* __restrict__ outp)
{
    __shared__ float wsh[64];
    const int tid = threadIdx.x;
    if (tid < 64) wsh[tid] = w_out[tid];
    __syncthreads();
    const int bt = blockIdx.x * 256 + tid;
    const uint4* hp = (const uint4*)(h1g + (size_t)bt * 64);
    float s = 0.0f;
    #pragma unroll
    for (int i = 0; i < 8; ++i) {
        uint4 v = hp[i];
        const float* wp = &wsh[8 * i];
        h2 p;
        p = BC(v.x); s = fmaf((float)p[0], wp[0], s); s = fmaf((float)p[1], wp[1], s);
        p = BC(v.y); s = fmaf((float)p[0], wp[2], s); s = fmaf((float)p[1], wp[3], s);
        p = BC(v.z); s = fmaf((float)p[0], wp[4], s); s = fmaf((float)p[1], wp[5], s);
        p = BC(v.w); s = fmaf((float)p[0], wp[6], s); s = fmaf((float)p[1], wp[7], s);
    }
    outp[bt] = __builtin_amdgcn_rcpf(1.0f + __expf(-(s + b_out[0])));
}

extern "C" void kernel_launch(void* const* d_in, const int* in_sizes, int n_in,
                              void* d_out, int out_size, void* d_ws, size_t ws_size,
                              hipStream_t stream) {
    const float* x     = (const float*)d_in[0];
    const float* w_ih0 = (const float*)d_in[1];
    const float* w_hh0 = (const float*)d_in[2];
    const float* b_ih0 = (const float*)d_in[3];
    const float* b_hh0 = (const float*)d_in[4];
    const float* w_ih1 = (const float*)d_in[5];
    const float* w_hh1 = (const float*)d_in[6];
    const float* b_ih1 = (const float*)d_in[7];
    const float* b_hh1 = (const float*)d_in[8];
    const float* w_out = (const float*)d_in[9];
    const float* b_out = (const float*)d_in[10];
    float* out = (float*)d_out;

    ushort* xg  = (ushort*)d_ws;                                   // 128 MiB
    ushort* h1g = (ushort*)((char*)d_ws + (size_t)BT * 256 * 2);   //  32 MiB

    hipLaunchKernelGGL(xg_mfma, dim3(BT / 256), dim3(256), 0, stream, x, w_ih0, xg);
    hipLaunchKernelGGL(lstm2_core, dim3(BB), dim3(192), 0, stream,
                       w_hh0, b_ih0, b_hh0, w_ih1, w_hh1, b_ih1, b_hh1, xg, h1g);
    hipLaunchKernelGGL(head_gemv, dim3(BT / 256), dim3(256), 0, stream,
                       h1g, w_out, b_out, out);
}